// Round 3
// baseline (581.733 us; speedup 1.0000x reference)
//
#include <hip/hip_runtime.h>
#include <cstdint>
#include <cstddef>

#define H 512
#define W 512
#define NPIX (H * W)          // 262144 = 2^18
#define TOPK 2048
#define CAND_CAP 4096
#define LIST_CAP 65536
#define NBATCH 2

#define RG 62                 // NMS tile region (32 + 2*15 halo)
#define RS 64                 // padded LDS row stride
#define NTOT (RG * RS)        // 3968
#define NPAIR (RG * 32)       // 1984 pair-items per full sweep

struct Tap {
    int x0, x1, y0, y1;
    float wx, wy;
    float pad0, pad1;
};

#define F2(arr, i) (*reinterpret_cast<float2*>(&(arr)[(i)]))
#define U16(arr, i) (*reinterpret_cast<unsigned short*>(&(arr)[(i)]))

// ---------------------------------------------------------------------------
// K0: zero hist + counters
__global__ void k_zero(unsigned int* __restrict__ hist, unsigned int* __restrict__ cnts) {
    int i = blockIdx.x * 256 + threadIdx.x;
    if (i < NBATCH * 65536) hist[i] = 0;
    if (i < 16) cnts[i] = 0;
}

// ---------------------------------------------------------------------------
// K1: fully-fused simple_nms in LDS (pair-wise sweeps), emitting surviving
// (value||~pix) composites directly to a global list + 16-bit-prefix histogram.
// Bit-exact float equality preserved; -inf padding == reduce_window clipping;
// H-split at 256 respected (tiles never straddle it).
__global__ __launch_bounds__(256) void k_nms_fused(
        const float* __restrict__ s,
        unsigned int* __restrict__ hist,
        unsigned long long* __restrict__ list,
        unsigned int* __restrict__ gcnt) {
    __shared__ float A[NTOT];            // s region (whole kernel)
    __shared__ float Bf[NTOT];           // ss
    __shared__ float Cf[NTOT];           // row-max temp
    __shared__ unsigned char Mmm[NTOT];  // mm
    __shared__ unsigned char Msm[NTOT];  // sm
    __shared__ unsigned char Mt[NTOT];   // row-OR temp

    const int tid = threadIdx.x;
    const int b = blockIdx.z;
    const int gx0 = blockIdx.x * 32 - 15;
    const int gy0 = blockIdx.y * 32 - 15;
    const int h0 = (blockIdx.y < 8) ? 0 : 256;
    const int h1 = h0 + 256;
    const float* sb = s + (size_t)b * NPIX;

    // load region with -inf padding
    for (int i = tid; i < NTOT; i += 256) {
        int x = i & 63, y = i >> 6;
        float v = -INFINITY;
        int gx = gx0 + x, gy = gy0 + y;
        if (x < RG && gx >= 0 && gx < W && gy >= h0 && gy < h1)
            v = sb[gy * W + gx];
        A[i] = v;
    }
    __syncthreads();

    // rowmax7(A) -> Cf : out x in [3,59), all rows (pairs)
    for (int pi = tid; pi < NPAIR; pi += 256) {
        int y = pi >> 5, x = (pi & 31) * 2;
        if (x < 2 || x > 58) continue;
        int i = y * RS + x;
        float2 a0 = F2(A, i - 2), a1 = F2(A, i), a2 = F2(A, i + 2);
        float c6 = fmaxf(fmaxf(fmaxf(a0.x, a0.y), fmaxf(a1.x, a1.y)), fmaxf(a2.x, a2.y));
        float lft = (i >= 3) ? A[i - 3] : -INFINITY;
        float o0 = fmaxf(c6, lft);
        float o1 = fmaxf(c6, A[i + 4]);
        if (x >= 3 && x < 59) Cf[i] = o0;
        if (x + 1 < 59) Cf[i + 1] = o1;      // x+1 >= 3 always here
    }
    __syncthreads();

    // mm0 = (A == colmax7(Cf)) : rect [3,59)^2 (pairs, per-elem predicate)
    for (int pi = tid; pi < NPAIR; pi += 256) {
        int y = pi >> 5, x = (pi & 31) * 2;
        if (y < 3 || y >= 59 || x < 2 || x > 58) continue;
        int i = y * RS + x;
        float2 m = F2(Cf, i - 3 * RS);
        float2 c;
        c = F2(Cf, i - 2 * RS); m.x = fmaxf(m.x, c.x); m.y = fmaxf(m.y, c.y);
        c = F2(Cf, i - RS);     m.x = fmaxf(m.x, c.x); m.y = fmaxf(m.y, c.y);
        c = F2(Cf, i);          m.x = fmaxf(m.x, c.x); m.y = fmaxf(m.y, c.y);
        c = F2(Cf, i + RS);     m.x = fmaxf(m.x, c.x); m.y = fmaxf(m.y, c.y);
        c = F2(Cf, i + 2 * RS); m.x = fmaxf(m.x, c.x); m.y = fmaxf(m.y, c.y);
        c = F2(Cf, i + 3 * RS); m.x = fmaxf(m.x, c.x); m.y = fmaxf(m.y, c.y);
        float2 a = F2(A, i);
        if (x >= 3 && x < 59)  Mmm[i] = (a.x == m.x) ? 1 : 0;
        if (x + 1 < 59)        Mmm[i + 1] = (a.y == m.y) ? 1 : 0;
    }
    __syncthreads();

    for (int it = 0; it < 2; ++it) {
        const int lo1 = 6 + 6 * it, hi1 = RG - lo1;   // even bounds
        const int lo0 = lo1 - 3,    hi0 = RG - lo0;
        const int lo2 = lo1 + 3,    hi2 = RG - lo2;   // odd bounds

        // rowOR7(Mmm) -> Mt : x in [lo1,hi1) (even-bounded, full pairs), y in [lo0,hi0)
        for (int pi = tid; pi < NPAIR; pi += 256) {
            int y = pi >> 5, x = (pi & 31) * 2;
            if (y < lo0 || y >= hi0 || x < lo1 || x >= hi1) continue;
            int i = y * RS + x;
            unsigned int u = (unsigned int)U16(Mmm, i - 2) | U16(Mmm, i) | U16(Mmm, i + 2);
            unsigned int common = (u | (u >> 8)) & 0xFF;
            unsigned int o0 = common | Mmm[i - 3];
            unsigned int o1 = common | Mmm[i + 4];
            U16(Mt, i) = (unsigned short)(o0 | (o1 << 8));
        }
        __syncthreads();

        // sm = colOR7(Mt); ss = sm ? 0 : s : rect [lo1,hi1)^2 (full pairs)
        for (int pi = tid; pi < NPAIR; pi += 256) {
            int y = pi >> 5, x = (pi & 31) * 2;
            if (y < lo1 || y >= hi1 || x < lo1 || x >= hi1) continue;
            int i = y * RS + x;
            unsigned int o = (unsigned int)U16(Mt, i - 3 * RS) | U16(Mt, i - 2 * RS) |
                             U16(Mt, i - RS) | U16(Mt, i) | U16(Mt, i + RS) |
                             U16(Mt, i + 2 * RS) | U16(Mt, i + 3 * RS);
            U16(Msm, i) = (unsigned short)o;
            float2 a = F2(A, i);
            float2 bb;
            bb.x = (o & 0xFF) ? 0.0f : a.x;
            bb.y = (o >> 8)   ? 0.0f : a.y;
            F2(Bf, i) = bb;
        }
        __syncthreads();

        // rowmax7(Bf) -> Cf : x in [lo2,hi2) (odd bounds), y in [lo1,hi1)
        for (int pi = tid; pi < NPAIR; pi += 256) {
            int y = pi >> 5, x = (pi & 31) * 2;
            if (y < lo1 || y >= hi1) continue;
            if (x + 1 < lo2 || x >= hi2) continue;
            int i = y * RS + x;
            float2 a0 = F2(Bf, i - 2), a1 = F2(Bf, i), a2 = F2(Bf, i + 2);
            float c6 = fmaxf(fmaxf(fmaxf(a0.x, a0.y), fmaxf(a1.x, a1.y)), fmaxf(a2.x, a2.y));
            float o0 = fmaxf(c6, Bf[i - 3]);
            float o1 = fmaxf(c6, Bf[i + 4]);
            if (x >= lo2 && x < hi2)     Cf[i] = o0;
            if (x + 1 >= lo2 && x + 1 < hi2) Cf[i + 1] = o1;
        }
        __syncthreads();

        if (it == 0) {
            // mm |= (Bf == colmax7(Cf)) & ~sm : rect [lo2,hi2)^2
            for (int pi = tid; pi < NPAIR; pi += 256) {
                int y = pi >> 5, x = (pi & 31) * 2;
                if (y < lo2 || y >= hi2) continue;
                if (x + 1 < lo2 || x >= hi2) continue;
                int i = y * RS + x;
                float2 m = F2(Cf, i - 3 * RS);
                float2 c;
                c = F2(Cf, i - 2 * RS); m.x = fmaxf(m.x, c.x); m.y = fmaxf(m.y, c.y);
                c = F2(Cf, i - RS);     m.x = fmaxf(m.x, c.x); m.y = fmaxf(m.y, c.y);
                c = F2(Cf, i);          m.x = fmaxf(m.x, c.x); m.y = fmaxf(m.y, c.y);
                c = F2(Cf, i + RS);     m.x = fmaxf(m.x, c.x); m.y = fmaxf(m.y, c.y);
                c = F2(Cf, i + 2 * RS); m.x = fmaxf(m.x, c.x); m.y = fmaxf(m.y, c.y);
                c = F2(Cf, i + 3 * RS); m.x = fmaxf(m.x, c.x); m.y = fmaxf(m.y, c.y);
                float2 bb = F2(Bf, i);
                if (x >= lo2 && x < hi2) {
                    int nm = (bb.x == m.x) ? 1 : 0;
                    Mmm[i] = (unsigned char)(Mmm[i] | (nm & (1 - (int)Msm[i])));
                }
                if (x + 1 >= lo2 && x + 1 < hi2) {
                    int nm = (bb.y == m.y) ? 1 : 0;
                    Mmm[i + 1] = (unsigned char)(Mmm[i + 1] | (nm & (1 - (int)Msm[i + 1])));
                }
            }
            __syncthreads();
        } else {
            // final: mm2 = mm | nm2 & ~sm2; emit candidates (border-masked)
            for (int pi = tid; pi < NPAIR; pi += 256) {
                int y = pi >> 5, x = (pi & 31) * 2;
                if (y < 15 || y >= 47) continue;
                if (x + 1 < 15 || x >= 47) continue;
                int i = y * RS + x;
                float2 m = F2(Cf, i - 3 * RS);
                float2 c;
                c = F2(Cf, i - 2 * RS); m.x = fmaxf(m.x, c.x); m.y = fmaxf(m.y, c.y);
                c = F2(Cf, i - RS);     m.x = fmaxf(m.x, c.x); m.y = fmaxf(m.y, c.y);
                c = F2(Cf, i);          m.x = fmaxf(m.x, c.x); m.y = fmaxf(m.y, c.y);
                c = F2(Cf, i + RS);     m.x = fmaxf(m.x, c.x); m.y = fmaxf(m.y, c.y);
                c = F2(Cf, i + 2 * RS); m.x = fmaxf(m.x, c.x); m.y = fmaxf(m.y, c.y);
                c = F2(Cf, i + 3 * RS); m.x = fmaxf(m.x, c.x); m.y = fmaxf(m.y, c.y);
                float2 bb = F2(Bf, i);
                float2 aa = F2(A, i);
                #pragma unroll
                for (int e = 0; e < 2; ++e) {
                    int xe = x + e;
                    if (xe < 15 || xe >= 47) continue;
                    float bv = e ? bb.y : bb.x;
                    float mv = e ? m.y : m.x;
                    float av = e ? aa.y : aa.x;
                    int nm = (bv == mv) ? 1 : 0;
                    int mm2 = Mmm[i + e] | (nm & (1 - (int)Msm[i + e]));
                    int gx = gx0 + xe, gy = gy0 + y;
                    bool border = (gx >= 3) && (gx < 510) && (gy >= 3) && (gy < 510);
                    float v = (mm2 && border) ? av : 0.0f;
                    if (v > 0.0f) {
                        unsigned int key = __float_as_uint(v);
                        atomicAdd(&hist[b * 65536 + (key >> 16)], 1u);
                        unsigned int pos = atomicAdd(&gcnt[b], 1u);
                        if (pos < LIST_CAP) {
                            unsigned int pix = (unsigned int)(gy * W + gx);
                            list[(size_t)b * LIST_CAP + pos] =
                                ((unsigned long long)key << 32) | (unsigned long long)(~pix);
                        }
                    }
                }
            }
        }
    }
}

// ---------------------------------------------------------------------------
// K2: threshold bucket via parallel suffix scans
__global__ __launch_bounds__(1024) void k_thresh(const unsigned int* __restrict__ hist,
                                                 unsigned int* __restrict__ tb) {
    int b = blockIdx.x;
    const unsigned int* h = hist + b * 65536;
    __shared__ unsigned int scan[1024];
    __shared__ int cstar;
    int t = threadIdx.x;

    unsigned int acc = 0;
    const uint4* h4 = reinterpret_cast<const uint4*>(h + t * 64);
    #pragma unroll
    for (int i = 0; i < 16; ++i) { uint4 v = h4[i]; acc += v.x + v.y + v.z + v.w; }
    scan[t] = acc;
    if (t == 0) cstar = -1;
    __syncthreads();
    for (int d = 1; d < 1024; d <<= 1) {
        unsigned int v = (t + d < 1024) ? scan[t + d] : 0;
        __syncthreads();
        scan[t] += v;
        __syncthreads();
    }
    unsigned int Snext = (t < 1023) ? scan[t + 1] : 0;
    if (scan[t] >= TOPK && (t == 1023 || Snext < TOPK)) cstar = t;
    __syncthreads();
    int c = cstar;
    if (c < 0) {
        if (t == 0) tb[b] = 0;
        return;
    }
    if (t < 64) {
        unsigned int above = (c < 1023) ? scan[c + 1] : 0;
        unsigned int suf = h[c * 64 + t];
        #pragma unroll
        for (int d = 1; d < 64; d <<= 1) {
            unsigned int v2 = __shfl_down(suf, d, 64);
            suf += (t + d < 64) ? v2 : 0;
        }
        bool cond = (above + suf) >= (unsigned int)TOPK;
        unsigned long long msk = __ballot(cond);
        if (t == 0) tb[b] = (unsigned int)(c * 64 + (63 - __clzll(msk)));
    }
}

// ---------------------------------------------------------------------------
// K3: filter candidate list by threshold bucket -> compact cand array
__global__ void k_filter(const unsigned long long* __restrict__ list,
                         const unsigned int* __restrict__ gcnt,
                         const unsigned int* __restrict__ tb,
                         unsigned long long* __restrict__ cand,
                         unsigned int* __restrict__ cnt2) {
    int i = blockIdx.x * 256 + threadIdx.x;
    int b = i >> 16;            // LIST_CAP = 65536
    int idx = i & (LIST_CAP - 1);
    unsigned int n = gcnt[b];
    if (n > LIST_CAP) n = LIST_CAP;
    if (idx >= (int)n) return;
    unsigned long long comp = list[(size_t)b * LIST_CAP + idx];
    unsigned int key = (unsigned int)(comp >> 32);
    if ((key >> 16) >= tb[b]) {
        unsigned int pos = atomicAdd(&cnt2[b], 1u);
        if (pos < CAND_CAP) cand[b * CAND_CAP + pos] = comp;
    }
}

// ---------------------------------------------------------------------------
// K4: rank-by-count top-k + fused 5x5 soft-argmax / disp / score bilinear.
// Composite keys are distinct -> exact jax.lax.top_k order (ties -> smaller idx).
__global__ __launch_bounds__(256) void k_rank_soft(
        const unsigned long long* __restrict__ cand,
        const unsigned int* __restrict__ cnt2,
        const float* __restrict__ s,
        float* __restrict__ out_kxy, float* __restrict__ out_sc,
        float* __restrict__ out_disp, Tap* __restrict__ taps) {
    __shared__ unsigned long long sk[CAND_CAP];   // 32 KB
    int b = blockIdx.y;
    int tid = threadIdx.x;
    unsigned int n = cnt2[b];
    if (n > CAND_CAP) n = CAND_CAP;
    const unsigned long long* cb = cand + b * CAND_CAP;
    for (int i = tid; i < CAND_CAP; i += 256)
        sk[i] = (i < (int)n) ? cb[i] : 0ULL;
    __syncthreads();
    int i = blockIdx.x * 256 + tid;
    if (i >= (int)n) return;
    unsigned long long my = sk[i];
    int rank = 0;
    int j = 0;
    int n4 = (int)n & ~3;
    for (; j < n4; j += 4)
        rank += (sk[j] > my) + (sk[j + 1] > my) + (sk[j + 2] > my) + (sk[j + 3] > my);
    for (; j < (int)n; ++j) rank += (sk[j] > my);
    if (rank >= TOPK) return;

    int t = b * TOPK + rank;
    unsigned int pix = ~(unsigned int)(my & 0xFFFFFFFFULL);
    int ky = (int)(pix >> 9) & 511, kx = (int)pix & 511;
    const float* sb = s + (size_t)b * NPIX;

    float p[25];
    float maxv = -INFINITY;
    #pragma unroll
    for (int ii = 0; ii < 5; ++ii)
        #pragma unroll
        for (int jj = 0; jj < 5; ++jj) {
            float v = sb[(ky - 2 + ii) * W + (kx - 2 + jj)];
            p[ii * 5 + jj] = v;
            maxv = fmaxf(maxv, v);
        }
    float e[25];
    float ssum = 0.0f, sx = 0.0f, sy = 0.0f;
    #pragma unroll
    for (int ii = 0; ii < 5; ++ii)
        #pragma unroll
        for (int jj = 0; jj < 5; ++jj) {
            float ev = expf((p[ii * 5 + jj] - maxv) / 0.1f);
            e[ii * 5 + jj] = ev;
            ssum += ev;
            sx += ev * (float)(jj - 2);
            sy += ev * (float)(ii - 2);
        }
    float xr = sx / ssum, yr = sy / ssum;
    float acc = 0.0f;
    #pragma unroll
    for (int ii = 0; ii < 5; ++ii)
        #pragma unroll
        for (int jj = 0; jj < 5; ++jj) {
            float dx = ((float)(jj - 2) - xr) * 0.5f;
            float dy = ((float)(ii - 2) - yr) * 0.5f;
            acc += e[ii * 5 + jj] * (dx * dx + dy * dy);
        }
    out_disp[t] = acc / ssum;

    float nx = ((float)kx + xr) / 511.0f * 2.0f - 1.0f;
    float ny = ((float)ky + yr) / 511.0f * 2.0f - 1.0f;
    float2 kxy; kxy.x = nx; kxy.y = ny;
    *reinterpret_cast<float2*>(&out_kxy[t * 2]) = kxy;

    float xp = (nx + 1.0f) * 0.5f * 511.0f;
    float yp = (ny + 1.0f) * 0.5f * 511.0f;
    float x0 = floorf(xp), y0 = floorf(yp);
    float wxf = xp - x0, wyf = yp - y0;
    int x0i = (int)fminf(fmaxf(x0, 0.0f), 511.0f);
    int x1i = (int)fminf(fmaxf(x0 + 1.0f, 0.0f), 511.0f);
    int y0i = (int)fminf(fmaxf(y0, 0.0f), 511.0f);
    int y1i = (int)fminf(fmaxf(y0 + 1.0f, 0.0f), 511.0f);
    float v00 = sb[y0i * W + x0i], v01 = sb[y0i * W + x1i];
    float v10 = sb[y1i * W + x0i], v11 = sb[y1i * W + x1i];
    out_sc[t] = v00 * (1.0f - wxf) * (1.0f - wyf) + v01 * wxf * (1.0f - wyf)
              + v10 * (1.0f - wxf) * wyf + v11 * wxf * wyf;

    Tap tp;
    tp.x0 = x0i; tp.x1 = x1i; tp.y0 = y0i; tp.y1 = y1i;
    tp.wx = wxf; tp.wy = wyf; tp.pad0 = 0.0f; tp.pad1 = 0.0f;
    taps[t] = tp;
}

// ---------------------------------------------------------------------------
// K5: one block per keypoint, 128 threads = 128 channels; bilinear + L2 norm
__global__ void k_desc(const float* __restrict__ dmap, const Tap* __restrict__ taps,
                       float* __restrict__ out_desc) {
    int t = blockIdx.x;          // 0..4095
    int b = t >> 11;
    int c = threadIdx.x;         // 0..127
    Tap tp = taps[t];
    const float* db = dmap + ((size_t)(b * 128 + c)) * NPIX;
    float w00 = (1.0f - tp.wx) * (1.0f - tp.wy);
    float w01 = tp.wx * (1.0f - tp.wy);
    float w10 = (1.0f - tp.wx) * tp.wy;
    float w11 = tp.wx * tp.wy;
    float v = db[tp.y0 * W + tp.x0] * w00 + db[tp.y0 * W + tp.x1] * w01
            + db[tp.y1 * W + tp.x0] * w10 + db[tp.y1 * W + tp.x1] * w11;

    float sq = v * v;
    #pragma unroll
    for (int m = 32; m >= 1; m >>= 1) sq += __shfl_xor(sq, m, 64);
    __shared__ float red[2];
    int wave = c >> 6, lane = c & 63;
    if (lane == 0) red[wave] = sq;
    __syncthreads();
    float tot = red[0] + red[1];
    float nrm = sqrtf(tot);
    float sc = 1.0f / fmaxf(nrm, 1e-12f);
    out_desc[(size_t)t * 128 + c] = v * sc;
}

extern "C" void kernel_launch(void* const* d_in, const int* in_sizes, int n_in,
                              void* d_out, int out_size, void* d_ws, size_t ws_size,
                              hipStream_t stream) {
    const float* s    = (const float*)d_in[0];   // (2,1,512,512)
    const float* dmap = (const float*)d_in[1];   // (2,128,512,512)
    float* out = (float*)d_out;
    float* out_kxy  = out;                          // 2*2048*2
    float* out_desc = out + 8192;                   // 2*2048*128
    float* out_sc   = out + 8192 + 524288;          // 2*2048
    float* out_disp = out_sc + 4096;                // 2*2048

    char* w = (char*)d_ws;
    unsigned int* hist       = (unsigned int*)w;       w += (size_t)NBATCH * 65536 * 4;
    unsigned long long* list = (unsigned long long*)w; w += (size_t)NBATCH * LIST_CAP * 8;
    unsigned long long* cand = (unsigned long long*)w; w += (size_t)NBATCH * CAND_CAP * 8;
    unsigned int* cnts       = (unsigned int*)w;       w += 256;   // [0..1]=gcnt, [2..3]=cnt2
    unsigned int* tb         = (unsigned int*)w;       w += 256;
    Tap* taps                = (Tap*)w;                w += (size_t)NBATCH * TOPK * sizeof(Tap);
    unsigned int* gcnt = cnts;
    unsigned int* cnt2 = cnts + 2;

    k_zero<<<dim3(512), dim3(256), 0, stream>>>(hist, cnts);
    k_nms_fused<<<dim3(16, 16, NBATCH), dim3(256), 0, stream>>>(s, hist, list, gcnt);
    k_thresh<<<dim3(NBATCH), dim3(1024), 0, stream>>>(hist, tb);
    k_filter<<<dim3((NBATCH * LIST_CAP) / 256), dim3(256), 0, stream>>>(list, gcnt, tb, cand, cnt2);
    k_rank_soft<<<dim3(CAND_CAP / 256, NBATCH), dim3(256), 0, stream>>>(cand, cnt2, s, out_kxy, out_sc, out_disp, taps);
    k_desc<<<dim3(NBATCH * TOPK), dim3(128), 0, stream>>>(dmap, taps, out_desc);
}

// Round 4
// 529.833 us; speedup vs baseline: 1.0980x; 1.0980x over previous
//
#include <hip/hip_runtime.h>
#include <cstdint>
#include <cstddef>

#define H 512
#define W 512
#define NPIX (H * W)          // 262144 = 2^18
#define TOPK 2048
#define CAND_CAP 4096
#define LIST_CAP 65536
#define NBATCH 2

#define RG 62                 // NMS tile region (32 + 2*15 halo)
#define RS 64                 // padded LDS row stride
#define NTOT (RG * RS)        // 3968
#define NPAIR (RG * 32)       // 1984 pair-items per full sweep

struct Tap {
    int x0, x1, y0, y1;
    float wx, wy;
    float pad0, pad1;
};

#define F2(arr, i) (*reinterpret_cast<float2*>(&(arr)[(i)]))
#define U16(arr, i) (*reinterpret_cast<unsigned short*>(&(arr)[(i)]))

// ---------------------------------------------------------------------------
// K0: zero hist + counters
__global__ void k_zero(unsigned int* __restrict__ hist, unsigned int* __restrict__ cnts) {
    int i = blockIdx.x * 256 + threadIdx.x;
    if (i < NBATCH * 65536) hist[i] = 0;
    if (i < 16) cnts[i] = 0;
}

// ---------------------------------------------------------------------------
// K1: fully-fused simple_nms in LDS (pair-wise sweeps), emitting surviving
// (value||~pix) composites directly to a global list + 16-bit-prefix histogram.
// Bit-exact vs reference: -inf padding == reduce_window edge clipping;
// H-split at 256 respected (tiles never straddle it).
__global__ __launch_bounds__(256) void k_nms_fused(
        const float* __restrict__ s,
        unsigned int* __restrict__ hist,
        unsigned long long* __restrict__ list,
        unsigned int* __restrict__ gcnt) {
    __shared__ float A[NTOT];            // s region (whole kernel)
    __shared__ float Bf[NTOT];           // ss
    __shared__ float Cf[NTOT];           // row-max temp
    __shared__ unsigned char Mmm[NTOT];  // mm
    __shared__ unsigned char Msm[NTOT];  // sm
    __shared__ unsigned char Mt[NTOT];   // row-OR temp

    const int tid = threadIdx.x;
    const int b = blockIdx.z;
    const int gx0 = blockIdx.x * 32 - 15;
    const int gy0 = blockIdx.y * 32 - 15;
    const int h0 = (blockIdx.y < 8) ? 0 : 256;
    const int h1 = h0 + 256;
    const float* sb = s + (size_t)b * NPIX;

    // load region with -inf padding
    for (int i = tid; i < NTOT; i += 256) {
        int x = i & 63, y = i >> 6;
        float v = -INFINITY;
        int gx = gx0 + x, gy = gy0 + y;
        if (x < RG && gx >= 0 && gx < W && gy >= h0 && gy < h1)
            v = sb[gy * W + gx];
        A[i] = v;
    }
    __syncthreads();

    // rowmax7(A) -> Cf : out x in [3,59), all rows (pairs)
    for (int pi = tid; pi < NPAIR; pi += 256) {
        int y = pi >> 5, x = (pi & 31) * 2;
        if (x < 2 || x > 58) continue;
        int i = y * RS + x;
        float2 a0 = F2(A, i - 2), a1 = F2(A, i), a2 = F2(A, i + 2);
        float c6 = fmaxf(fmaxf(fmaxf(a0.x, a0.y), fmaxf(a1.x, a1.y)), fmaxf(a2.x, a2.y));
        float lft = (i >= 3) ? A[i - 3] : -INFINITY;
        float o0 = fmaxf(c6, lft);
        float o1 = fmaxf(c6, A[i + 4]);
        if (x >= 3 && x < 59) Cf[i] = o0;
        if (x + 1 < 59) Cf[i + 1] = o1;      // x+1 >= 3 always here
    }
    __syncthreads();

    // mm0 = (A == colmax7(Cf)) : rect [3,59)^2 (pairs, per-elem predicate)
    for (int pi = tid; pi < NPAIR; pi += 256) {
        int y = pi >> 5, x = (pi & 31) * 2;
        if (y < 3 || y >= 59 || x < 2 || x > 58) continue;
        int i = y * RS + x;
        float2 m = F2(Cf, i - 3 * RS);
        float2 c;
        c = F2(Cf, i - 2 * RS); m.x = fmaxf(m.x, c.x); m.y = fmaxf(m.y, c.y);
        c = F2(Cf, i - RS);     m.x = fmaxf(m.x, c.x); m.y = fmaxf(m.y, c.y);
        c = F2(Cf, i);          m.x = fmaxf(m.x, c.x); m.y = fmaxf(m.y, c.y);
        c = F2(Cf, i + RS);     m.x = fmaxf(m.x, c.x); m.y = fmaxf(m.y, c.y);
        c = F2(Cf, i + 2 * RS); m.x = fmaxf(m.x, c.x); m.y = fmaxf(m.y, c.y);
        c = F2(Cf, i + 3 * RS); m.x = fmaxf(m.x, c.x); m.y = fmaxf(m.y, c.y);
        float2 a = F2(A, i);
        if (x >= 3 && x < 59)  Mmm[i] = (a.x == m.x) ? 1 : 0;
        if (x + 1 < 59)        Mmm[i + 1] = (a.y == m.y) ? 1 : 0;
    }
    __syncthreads();

    for (int it = 0; it < 2; ++it) {
        const int lo1 = 6 + 6 * it, hi1 = RG - lo1;   // even bounds
        const int lo0 = lo1 - 3,    hi0 = RG - lo0;
        const int lo2 = lo1 + 3,    hi2 = RG - lo2;   // odd bounds

        // rowOR7(Mmm) -> Mt : x in [lo1,hi1), y in [lo0,hi0)
        for (int pi = tid; pi < NPAIR; pi += 256) {
            int y = pi >> 5, x = (pi & 31) * 2;
            if (y < lo0 || y >= hi0 || x < lo1 || x >= hi1) continue;
            int i = y * RS + x;
            unsigned int u = (unsigned int)U16(Mmm, i - 2) | U16(Mmm, i) | U16(Mmm, i + 2);
            unsigned int common = (u | (u >> 8)) & 0xFF;
            unsigned int o0 = common | Mmm[i - 3];
            unsigned int o1 = common | Mmm[i + 4];
            U16(Mt, i) = (unsigned short)(o0 | (o1 << 8));
        }
        __syncthreads();

        // sm = colOR7(Mt); ss = sm ? 0 : s : rect [lo1,hi1)^2 (full pairs)
        for (int pi = tid; pi < NPAIR; pi += 256) {
            int y = pi >> 5, x = (pi & 31) * 2;
            if (y < lo1 || y >= hi1 || x < lo1 || x >= hi1) continue;
            int i = y * RS + x;
            unsigned int o = (unsigned int)U16(Mt, i - 3 * RS) | U16(Mt, i - 2 * RS) |
                             U16(Mt, i - RS) | U16(Mt, i) | U16(Mt, i + RS) |
                             U16(Mt, i + 2 * RS) | U16(Mt, i + 3 * RS);
            U16(Msm, i) = (unsigned short)o;
            float2 a = F2(A, i);
            float2 bb;
            bb.x = (o & 0xFF) ? 0.0f : a.x;
            bb.y = (o >> 8)   ? 0.0f : a.y;
            F2(Bf, i) = bb;
        }
        __syncthreads();

        // rowmax7(Bf) -> Cf : x in [lo2,hi2) (odd bounds), y in [lo1,hi1)
        for (int pi = tid; pi < NPAIR; pi += 256) {
            int y = pi >> 5, x = (pi & 31) * 2;
            if (y < lo1 || y >= hi1) continue;
            if (x + 1 < lo2 || x >= hi2) continue;
            int i = y * RS + x;
            float2 a0 = F2(Bf, i - 2), a1 = F2(Bf, i), a2 = F2(Bf, i + 2);
            float c6 = fmaxf(fmaxf(fmaxf(a0.x, a0.y), fmaxf(a1.x, a1.y)), fmaxf(a2.x, a2.y));
            float o0 = fmaxf(c6, Bf[i - 3]);
            float o1 = fmaxf(c6, Bf[i + 4]);
            if (x >= lo2 && x < hi2)     Cf[i] = o0;
            if (x + 1 >= lo2 && x + 1 < hi2) Cf[i + 1] = o1;
        }
        __syncthreads();

        if (it == 0) {
            // mm |= (Bf == colmax7(Cf)) & ~sm : rect [lo2,hi2)^2
            for (int pi = tid; pi < NPAIR; pi += 256) {
                int y = pi >> 5, x = (pi & 31) * 2;
                if (y < lo2 || y >= hi2) continue;
                if (x + 1 < lo2 || x >= hi2) continue;
                int i = y * RS + x;
                float2 m = F2(Cf, i - 3 * RS);
                float2 c;
                c = F2(Cf, i - 2 * RS); m.x = fmaxf(m.x, c.x); m.y = fmaxf(m.y, c.y);
                c = F2(Cf, i - RS);     m.x = fmaxf(m.x, c.x); m.y = fmaxf(m.y, c.y);
                c = F2(Cf, i);          m.x = fmaxf(m.x, c.x); m.y = fmaxf(m.y, c.y);
                c = F2(Cf, i + RS);     m.x = fmaxf(m.x, c.x); m.y = fmaxf(m.y, c.y);
                c = F2(Cf, i + 2 * RS); m.x = fmaxf(m.x, c.x); m.y = fmaxf(m.y, c.y);
                c = F2(Cf, i + 3 * RS); m.x = fmaxf(m.x, c.x); m.y = fmaxf(m.y, c.y);
                float2 bb = F2(Bf, i);
                if (x >= lo2 && x < hi2) {
                    int nm = (bb.x == m.x) ? 1 : 0;
                    Mmm[i] = (unsigned char)(Mmm[i] | (nm & (1 - (int)Msm[i])));
                }
                if (x + 1 >= lo2 && x + 1 < hi2) {
                    int nm = (bb.y == m.y) ? 1 : 0;
                    Mmm[i + 1] = (unsigned char)(Mmm[i + 1] | (nm & (1 - (int)Msm[i + 1])));
                }
            }
            __syncthreads();
        } else {
            // final: mm2 = mm | nm2 & ~sm2; emit candidates (border-masked)
            for (int pi = tid; pi < NPAIR; pi += 256) {
                int y = pi >> 5, x = (pi & 31) * 2;
                if (y < 15 || y >= 47) continue;
                if (x + 1 < 15 || x >= 47) continue;
                int i = y * RS + x;
                float2 m = F2(Cf, i - 3 * RS);
                float2 c;
                c = F2(Cf, i - 2 * RS); m.x = fmaxf(m.x, c.x); m.y = fmaxf(m.y, c.y);
                c = F2(Cf, i - RS);     m.x = fmaxf(m.x, c.x); m.y = fmaxf(m.y, c.y);
                c = F2(Cf, i);          m.x = fmaxf(m.x, c.x); m.y = fmaxf(m.y, c.y);
                c = F2(Cf, i + RS);     m.x = fmaxf(m.x, c.x); m.y = fmaxf(m.y, c.y);
                c = F2(Cf, i + 2 * RS); m.x = fmaxf(m.x, c.x); m.y = fmaxf(m.y, c.y);
                c = F2(Cf, i + 3 * RS); m.x = fmaxf(m.x, c.x); m.y = fmaxf(m.y, c.y);
                float2 bb = F2(Bf, i);
                float2 aa = F2(A, i);
                #pragma unroll
                for (int e = 0; e < 2; ++e) {
                    int xe = x + e;
                    if (xe < 15 || xe >= 47) continue;
                    float bv = e ? bb.y : bb.x;
                    float mv = e ? m.y : m.x;
                    float av = e ? aa.y : aa.x;
                    int nm = (bv == mv) ? 1 : 0;
                    int mm2 = Mmm[i + e] | (nm & (1 - (int)Msm[i + e]));
                    int gx = gx0 + xe, gy = gy0 + y;
                    bool border = (gx >= 3) && (gx < 510) && (gy >= 3) && (gy < 510);
                    float v = (mm2 && border) ? av : 0.0f;
                    if (v > 0.0f) {
                        unsigned int key = __float_as_uint(v);
                        atomicAdd(&hist[b * 65536 + (key >> 16)], 1u);
                        unsigned int pos = atomicAdd(&gcnt[b], 1u);
                        if (pos < LIST_CAP) {
                            unsigned int pix = (unsigned int)(gy * W + gx);
                            list[(size_t)b * LIST_CAP + pos] =
                                ((unsigned long long)key << 32) | (unsigned long long)(~pix);
                        }
                    }
                }
            }
        }
    }
}

// ---------------------------------------------------------------------------
// K2: fused threshold-bucket + list filter (one block per batch, 1024 thr).
// Phase 1: suffix scans over the 65536-bin histogram -> threshold bucket.
// Phase 2: compact all list entries with bucket >= tb into cand (LDS counter).
__global__ __launch_bounds__(1024) void k_thresh_filter(
        const unsigned int* __restrict__ hist,
        const unsigned long long* __restrict__ list,
        const unsigned int* __restrict__ gcnt,
        unsigned long long* __restrict__ cand,
        unsigned int* __restrict__ cnt2) {
    int b = blockIdx.x;
    const unsigned int* h = hist + b * 65536;
    __shared__ unsigned int scan[1024];
    __shared__ int cstar;
    __shared__ unsigned int s_tb;
    __shared__ unsigned int s_cnt;
    int t = threadIdx.x;

    unsigned int acc = 0;
    const uint4* h4 = reinterpret_cast<const uint4*>(h + t * 64);
    #pragma unroll
    for (int i = 0; i < 16; ++i) { uint4 v = h4[i]; acc += v.x + v.y + v.z + v.w; }
    scan[t] = acc;
    if (t == 0) { cstar = -1; s_tb = 0; s_cnt = 0; }
    __syncthreads();
    for (int d = 1; d < 1024; d <<= 1) {
        unsigned int v = (t + d < 1024) ? scan[t + d] : 0;
        __syncthreads();
        scan[t] += v;
        __syncthreads();
    }
    unsigned int Snext = (t < 1023) ? scan[t + 1] : 0;
    if (scan[t] >= TOPK && (t == 1023 || Snext < TOPK)) cstar = t;
    __syncthreads();
    int c = cstar;
    if (c >= 0 && t < 64) {
        unsigned int above = (c < 1023) ? scan[c + 1] : 0;
        unsigned int suf = h[c * 64 + t];
        #pragma unroll
        for (int d = 1; d < 64; d <<= 1) {
            unsigned int v2 = __shfl_down(suf, d, 64);
            suf += (t + d < 64) ? v2 : 0;
        }
        bool cond = (above + suf) >= (unsigned int)TOPK;
        unsigned long long msk = __ballot(cond);
        if (t == 0) s_tb = (unsigned int)(c * 64 + (63 - __clzll(msk)));
    }
    __syncthreads();
    unsigned int tbv = s_tb;

    unsigned int n = gcnt[b];
    if (n > LIST_CAP) n = LIST_CAP;
    const unsigned long long* lb = list + (size_t)b * LIST_CAP;
    for (unsigned int idx = t; idx < n; idx += 1024) {
        unsigned long long comp = lb[idx];
        if ((unsigned int)(comp >> 48) >= tbv) {
            unsigned int pos = atomicAdd(&s_cnt, 1u);
            if (pos < CAND_CAP) cand[b * CAND_CAP + pos] = comp;
        }
    }
    __syncthreads();
    if (t == 0) cnt2[b] = (s_cnt < CAND_CAP) ? s_cnt : CAND_CAP;
}

// ---------------------------------------------------------------------------
// K3: rank-by-count top-k + fused 5x5 soft-argmax / disp / score bilinear.
// Composite keys distinct -> exact jax.lax.top_k order (ties -> smaller idx).
__global__ __launch_bounds__(256) void k_rank_soft(
        const unsigned long long* __restrict__ cand,
        const unsigned int* __restrict__ cnt2,
        const float* __restrict__ s,
        float* __restrict__ out_kxy, float* __restrict__ out_sc,
        float* __restrict__ out_disp, Tap* __restrict__ taps) {
    __shared__ unsigned long long sk[CAND_CAP];   // 32 KB
    int b = blockIdx.y;
    int tid = threadIdx.x;
    unsigned int n = cnt2[b];
    if (n > CAND_CAP) n = CAND_CAP;
    const unsigned long long* cb = cand + b * CAND_CAP;
    for (int i = tid; i < CAND_CAP; i += 256)
        sk[i] = (i < (int)n) ? cb[i] : 0ULL;
    __syncthreads();
    int i = blockIdx.x * 256 + tid;
    if (i >= (int)n) return;
    unsigned long long my = sk[i];
    int rank = 0;
    int j = 0;
    int n4 = (int)n & ~3;
    for (; j < n4; j += 4)
        rank += (sk[j] > my) + (sk[j + 1] > my) + (sk[j + 2] > my) + (sk[j + 3] > my);
    for (; j < (int)n; ++j) rank += (sk[j] > my);
    if (rank >= TOPK) return;

    int t = b * TOPK + rank;
    unsigned int pix = ~(unsigned int)(my & 0xFFFFFFFFULL);
    int ky = (int)(pix >> 9) & 511, kx = (int)pix & 511;
    const float* sb = s + (size_t)b * NPIX;

    float p[25];
    float maxv = -INFINITY;
    #pragma unroll
    for (int ii = 0; ii < 5; ++ii)
        #pragma unroll
        for (int jj = 0; jj < 5; ++jj) {
            float v = sb[(ky - 2 + ii) * W + (kx - 2 + jj)];
            p[ii * 5 + jj] = v;
            maxv = fmaxf(maxv, v);
        }
    float e[25];
    float ssum = 0.0f, sx = 0.0f, sy = 0.0f;
    #pragma unroll
    for (int ii = 0; ii < 5; ++ii)
        #pragma unroll
        for (int jj = 0; jj < 5; ++jj) {
            float ev = expf((p[ii * 5 + jj] - maxv) / 0.1f);
            e[ii * 5 + jj] = ev;
            ssum += ev;
            sx += ev * (float)(jj - 2);
            sy += ev * (float)(ii - 2);
        }
    float xr = sx / ssum, yr = sy / ssum;
    float acc = 0.0f;
    #pragma unroll
    for (int ii = 0; ii < 5; ++ii)
        #pragma unroll
        for (int jj = 0; jj < 5; ++jj) {
            float dx = ((float)(jj - 2) - xr) * 0.5f;
            float dy = ((float)(ii - 2) - yr) * 0.5f;
            acc += e[ii * 5 + jj] * (dx * dx + dy * dy);
        }
    out_disp[t] = acc / ssum;

    float nx = ((float)kx + xr) / 511.0f * 2.0f - 1.0f;
    float ny = ((float)ky + yr) / 511.0f * 2.0f - 1.0f;
    float2 kxy; kxy.x = nx; kxy.y = ny;
    *reinterpret_cast<float2*>(&out_kxy[t * 2]) = kxy;

    float xp = (nx + 1.0f) * 0.5f * 511.0f;
    float yp = (ny + 1.0f) * 0.5f * 511.0f;
    float x0 = floorf(xp), y0 = floorf(yp);
    float wxf = xp - x0, wyf = yp - y0;
    int x0i = (int)fminf(fmaxf(x0, 0.0f), 511.0f);
    int x1i = (int)fminf(fmaxf(x0 + 1.0f, 0.0f), 511.0f);
    int y0i = (int)fminf(fmaxf(y0, 0.0f), 511.0f);
    int y1i = (int)fminf(fmaxf(y0 + 1.0f, 0.0f), 511.0f);
    float v00 = sb[y0i * W + x0i], v01 = sb[y0i * W + x1i];
    float v10 = sb[y1i * W + x0i], v11 = sb[y1i * W + x1i];
    out_sc[t] = v00 * (1.0f - wxf) * (1.0f - wyf) + v01 * wxf * (1.0f - wyf)
              + v10 * (1.0f - wxf) * wyf + v11 * wxf * wyf;

    Tap tp;
    tp.x0 = x0i; tp.x1 = x1i; tp.y0 = y0i; tp.y1 = y1i;
    tp.wx = wxf; tp.wy = wyf; tp.pad0 = 0.0f; tp.pad1 = 0.0f;
    taps[t] = tp;
}

// ---------------------------------------------------------------------------
// K4: one block per keypoint, 128 threads = 128 channels; bilinear + L2 norm
__global__ void k_desc(const float* __restrict__ dmap, const Tap* __restrict__ taps,
                       float* __restrict__ out_desc) {
    int t = blockIdx.x;          // 0..4095
    int b = t >> 11;
    int c = threadIdx.x;         // 0..127
    Tap tp = taps[t];
    const float* db = dmap + ((size_t)(b * 128 + c)) * NPIX;
    float w00 = (1.0f - tp.wx) * (1.0f - tp.wy);
    float w01 = tp.wx * (1.0f - tp.wy);
    float w10 = (1.0f - tp.wx) * tp.wy;
    float w11 = tp.wx * tp.wy;
    float v = db[tp.y0 * W + tp.x0] * w00 + db[tp.y0 * W + tp.x1] * w01
            + db[tp.y1 * W + tp.x0] * w10 + db[tp.y1 * W + tp.x1] * w11;

    float sq = v * v;
    #pragma unroll
    for (int m = 32; m >= 1; m >>= 1) sq += __shfl_xor(sq, m, 64);
    __shared__ float red[2];
    int wave = c >> 6, lane = c & 63;
    if (lane == 0) red[wave] = sq;
    __syncthreads();
    float tot = red[0] + red[1];
    float nrm = sqrtf(tot);
    float sc = 1.0f / fmaxf(nrm, 1e-12f);
    out_desc[(size_t)t * 128 + c] = v * sc;
}

extern "C" void kernel_launch(void* const* d_in, const int* in_sizes, int n_in,
                              void* d_out, int out_size, void* d_ws, size_t ws_size,
                              hipStream_t stream) {
    const float* s    = (const float*)d_in[0];   // (2,1,512,512)
    const float* dmap = (const float*)d_in[1];   // (2,128,512,512)
    float* out = (float*)d_out;
    float* out_kxy  = out;                          // 2*2048*2
    float* out_desc = out + 8192;                   // 2*2048*128
    float* out_sc   = out + 8192 + 524288;          // 2*2048
    float* out_disp = out_sc + 4096;                // 2*2048

    char* w = (char*)d_ws;
    unsigned int* hist       = (unsigned int*)w;       w += (size_t)NBATCH * 65536 * 4;
    unsigned long long* list = (unsigned long long*)w; w += (size_t)NBATCH * LIST_CAP * 8;
    unsigned long long* cand = (unsigned long long*)w; w += (size_t)NBATCH * CAND_CAP * 8;
    unsigned int* cnts       = (unsigned int*)w;       w += 256;   // [0..1]=gcnt, [2..3]=cnt2
    Tap* taps                = (Tap*)w;                w += (size_t)NBATCH * TOPK * sizeof(Tap);
    unsigned int* gcnt = cnts;
    unsigned int* cnt2 = cnts + 2;

    k_zero<<<dim3(512), dim3(256), 0, stream>>>(hist, cnts);
    k_nms_fused<<<dim3(16, 16, NBATCH), dim3(256), 0, stream>>>(s, hist, list, gcnt);
    k_thresh_filter<<<dim3(NBATCH), dim3(1024), 0, stream>>>(hist, list, gcnt, cand, cnt2);
    k_rank_soft<<<dim3(CAND_CAP / 256, NBATCH), dim3(256), 0, stream>>>(cand, cnt2, s, out_kxy, out_sc, out_disp, taps);
    k_desc<<<dim3(NBATCH * TOPK), dim3(128), 0, stream>>>(dmap, taps, out_desc);
}